// Round 9
// baseline (168.622 us; speedup 1.0000x reference)
//
#include <hip/hip_runtime.h>
#include <math.h>

#define B_ 4
#define C_ 128
#define CI_ 64
#define H_ 96
#define W_ 96
#define HW_ (H_*W_)      // 9216
#define NP_ 2304         // 48*48
#define GROUPS_ 32
#define EPS_ 1e-5f
#define KVT_ 32          // KV tile rows
#define NT_ (NP_/KVT_)   // 72 tiles

typedef _Float16 f16x8 __attribute__((ext_vector_type(8)));
typedef _Float16 f16x2 __attribute__((ext_vector_type(2)));
typedef __attribute__((ext_vector_type(4))) float f32x4;

__device__ inline f32x4 mfma16h(f16x8 a, f16x8 b, f32x4 c) {
    return __builtin_amdgcn_mfma_f32_16x16x32_f16(a, b, c, 0, 0, 0);
}
__device__ inline float h2f(unsigned short s) {
    return (float)__builtin_bit_cast(_Float16, s);
}
__device__ inline unsigned pk_f16(float a, float b) {     // pack 2 f32 -> 2 f16 (RTZ)
    return __builtin_bit_cast(unsigned, __builtin_amdgcn_cvt_pkrtz(a, b));
}
// global -> LDS direct DMA, 16B/lane. LDS dest = wave-uniform base + lane*16.
__device__ inline void gload_lds16(const void* g, void* l) {
    __builtin_amdgcn_global_load_lds(
        (const __attribute__((address_space(1))) void*)reinterpret_cast<uintptr_t>(g),
        (__attribute__((address_space(3))) void*)(unsigned)reinterpret_cast<uintptr_t>(l),
        16, 0, 0);
}

// ---------------------------------------------------------------------------
// Kernel 1: fused 3-way 1x1 conv projections -> fp16 [b][n][ci]
// ---------------------------------------------------------------------------
__global__ __launch_bounds__(256) void proj_kernel(
    const float* __restrict__ x,
    const float* __restrict__ w_theta, const float* __restrict__ b_theta,
    const float* __restrict__ w_phi,   const float* __restrict__ b_phi,
    const float* __restrict__ w_g,     const float* __restrict__ b_g,
    unsigned short* __restrict__ Qo, unsigned short* __restrict__ phiF,
    unsigned short* __restrict__ gF)
{
    __shared__ float xs[C_ * 32];   // xs[c*32 + pix]
    __shared__ float ws[C_ * 68];   // ws[c*68 + ci]
    const int t    = threadIdx.x;
    const int tile = blockIdx.x;
    const int b    = blockIdx.y;
    const int mat  = blockIdx.z;
    const float* wsel = (mat == 0) ? w_theta : (mat == 1) ? w_phi : w_g;
    const float* bsel = (mat == 0) ? b_theta : (mat == 1) ? b_phi : b_g;
    unsigned short* osel = (mat == 0) ? Qo : (mat == 1) ? phiF : gF;
    const int n0 = tile * 32;

    {
        const int pix = t & 31;
        const int c0  = t >> 5;
        const float* xb = x + (size_t)b * C_ * HW_ + n0 + pix;
        for (int c = c0; c < C_; c += 8)
            xs[c * 32 + pix] = xb[(size_t)c * HW_];
    }
    for (int j = t; j < CI_ * C_; j += 256)
        ws[(j & 127) * 68 + (j >> 7)] = wsel[j];
    __syncthreads();

    const int tp = (t & 7) * 4;
    const int tc = (t >> 3) * 2;
    float acc[4][2] = {};
    #pragma unroll 4
    for (int c = 0; c < C_; ++c) {
        const float4 xv = *(const float4*)&xs[c * 32 + tp];
        const float2 wv = *(const float2*)&ws[c * 68 + tc];
        const float xa[4] = {xv.x, xv.y, xv.z, xv.w};
        #pragma unroll
        for (int i = 0; i < 4; ++i) {
            acc[i][0] += xa[i] * wv.x;
            acc[i][1] += xa[i] * wv.y;
        }
    }
    const float2 bb = *(const float2*)&bsel[tc];
    #pragma unroll
    for (int i = 0; i < 4; ++i) {
        f16x2 hv = { (_Float16)(acc[i][0] + bb.x), (_Float16)(acc[i][1] + bb.y) };
        *(f16x2*)&osel[((size_t)b * HW_ + n0 + tp + i) * CI_ + tc] = hv;
    }
}

// ---------------------------------------------------------------------------
// Kernel 2: 2x2 maxpool (fp16 in/out, exact). K stays [b][m][ci]; V -> [b][ci][m].
// ---------------------------------------------------------------------------
__global__ __launch_bounds__(256) void pool_kernel(
    const unsigned short* __restrict__ phiF, const unsigned short* __restrict__ gF,
    unsigned short* __restrict__ Ko, unsigned short* __restrict__ Vt)
{
    const int t   = threadIdx.x;
    const int b   = blockIdx.y;
    const int mat = blockIdx.z;                 // 0 -> K, 1 -> V^T
    const int idx = blockIdx.x * 256 + t;       // 0..147455
    int m, ci;
    if (mat == 0) { m = idx >> 6; ci = idx & 63; }
    else          { ci = idx / NP_; m = idx - ci * NP_; }
    const int ph = m / 48, pw = m % 48;
    const int n00 = (ph * 2) * W_ + pw * 2;
    const unsigned short* src = mat ? gF : phiF;
    const unsigned short* p = src + ((size_t)b * HW_ + n00) * CI_ + ci;
    float v = fmaxf(fmaxf(h2f(p[0]), h2f(p[CI_])),
                    fmaxf(h2f(p[(size_t)W_ * CI_]), h2f(p[(size_t)(W_ + 1) * CI_])));
    unsigned short r = __builtin_bit_cast(unsigned short, (_Float16)v); // exact
    if (mat == 0) Ko[((size_t)b * NP_ + m) * CI_ + ci] = r;
    else          Vt[((size_t)b * CI_ + ci) * NP_ + m] = r;
}

// ---------------------------------------------------------------------------
// Kernel 3: fp16 MFMA flash attention — single-wave blocks, barrier-FREE.
// 16 q-rows/wave, 2304 waves = 9/CU (LDS 17.7 KB -> 9 blocks/CU resident).
// Wave-private double-buffered K/V staged by global_load_lds; per-wave counted
// s_waitcnt vmcnt(8) (drain-to-0 only on the last tile). Vote-based defer-max:
// common path has NO cross-lane ops. XOR swizzles both-sides (rule 21).
// ---------------------------------------------------------------------------
__global__ __launch_bounds__(64) void attn_kernel(
    const unsigned short* __restrict__ Qg, const unsigned short* __restrict__ Kg,
    const unsigned short* __restrict__ Vt, float* __restrict__ Yg)
{
    __shared__ unsigned char Klds[2][4096];   // [buf][32 k-rows x 128B]
    __shared__ unsigned char Vlds[2][4096];   // [buf][64 d-rows x  64B]
    __shared__ unsigned char Ps[16 * 80];     // P repack, 80B row stride

    const int lane = threadIdx.x;
    const int lr   = lane & 15;
    const int lg   = lane >> 4;
    const int b    = blockIdx.y;
    const int q0   = blockIdx.x * 16;

    // staging lane constants (inverse-swizzled global chunk per rule 21)
    const int krow = lane >> 3;                       // 0..7 (K: 8 rows/load)
    const int kchk = (lane & 7) ^ krow;               // K source 16B-chunk
    const int vrow = lane >> 2;                       // 0..15 (V: 16 rows/load)
    const int vchk = (lane & 3) ^ (vrow & 3);         // V source 16B-chunk

    const unsigned short* Kb = Kg + (size_t)b * NP_ * CI_;
    const unsigned short* Vb = Vt + (size_t)b * CI_ * NP_;

    // Q fragments: u in {0,1} d-halves
    f16x8 qf[2];
    #pragma unroll
    for (int u = 0; u < 2; ++u)
        qf[u] = *(const f16x8*)(Qg + ((size_t)b * HW_ + q0 + lr) * CI_ + u * 32 + lg * 8);

    f32x4 o_acc[4];
    #pragma unroll
    for (int dt = 0; dt < 4; ++dt) o_acc[dt] = (f32x4){0.f, 0.f, 0.f, 0.f};
    float mrun = -1e30f, lrun = 0.f;    // lrun = per-lane partial (reduced at end)

#define STAGE(BUF, TT)                                                          \
    {                                                                           \
        const int kv0_ = (TT) * KVT_;                                           \
        _Pragma("unroll")                                                       \
        for (int i = 0; i < 4; ++i)                                             \
            gload_lds16(Kb + (size_t)(kv0_ + 8 * i + krow) * CI_ + kchk * 8,    \
                        &Klds[BUF][i * 1024]);                                  \
        _Pragma("unroll")                                                       \
        for (int i = 0; i < 4; ++i)                                             \
            gload_lds16(Vb + (size_t)(16 * i + vrow) * NP_ + kv0_ + vchk * 8,   \
                        &Vlds[BUF][i * 1024]);                                  \
    }

#define COMPUTE(BUF)                                                            \
    {                                                                           \
        /* K fragments: kf[u][k4] = K[k4*16+lr][u*32 + lg*8 ..], swizzled */    \
        f16x8 kf[2][2];                                                         \
        _Pragma("unroll")                                                       \
        for (int u = 0; u < 2; ++u)                                             \
            _Pragma("unroll")                                                   \
            for (int k4 = 0; k4 < 2; ++k4)                                      \
                kf[u][k4] = *(const f16x8*)&Klds[BUF][(k4 * 16 + lr) * 128      \
                                + (((4 * u + lg) ^ (lr & 7)) << 4)];            \
        f32x4 s[2];                                                             \
        s[0] = (f32x4){0.f, 0.f, 0.f, 0.f};                                     \
        s[1] = (f32x4){0.f, 0.f, 0.f, 0.f};                                     \
        __builtin_amdgcn_s_setprio(1);                                          \
        _Pragma("unroll")                                                       \
        for (int u = 0; u < 2; ++u) {                                           \
            s[0] = mfma16h(kf[u][0], qf[u], s[0]);                              \
            s[1] = mfma16h(kf[u][1], qf[u], s[1]);                              \
        }                                                                       \
        __builtin_amdgcn_s_setprio(0);                                          \
        /* vote-based defer-max: no cross-lane in common path */                \
        float tmax = fmaxf(fmaxf(fmaxf(s[0][0], s[0][1]),                       \
                                 fmaxf(s[0][2], s[0][3])),                      \
                           fmaxf(fmaxf(s[1][0], s[1][1]),                       \
                                 fmaxf(s[1][2], s[1][3])));                     \
        if (!__all(tmax <= mrun + 8.0f)) {                                      \
            tmax = fmaxf(tmax, __shfl_xor(tmax, 16));                           \
            tmax = fmaxf(tmax, __shfl_xor(tmax, 32));                           \
            const float mnew = fmaxf(mrun, tmax);                               \
            const float sc = __expf(mrun - mnew);                               \
            lrun *= sc;                                                         \
            _Pragma("unroll")                                                   \
            for (int r2 = 0; r2 < 4; ++r2) {                                    \
                const float scb = __shfl(sc, 4 * lg + r2);                      \
                _Pragma("unroll")                                               \
                for (int dt = 0; dt < 4; ++dt) o_acc[dt][r2] *= scb;            \
            }                                                                   \
            mrun = mnew;                                                        \
        }                                                                       \
        /* P = exp(S - m); per-lane partial sum; pack to LDS */                 \
        _Pragma("unroll")                                                       \
        for (int k4 = 0; k4 < 2; ++k4) {                                        \
            const float e0 = __expf(s[k4][0] - mrun);                           \
            const float e1 = __expf(s[k4][1] - mrun);                           \
            const float e2 = __expf(s[k4][2] - mrun);                           \
            const float e3 = __expf(s[k4][3] - mrun);                           \
            lrun += (e0 + e1) + (e2 + e3);                                      \
            uint2 pk = { pk_f16(e0, e1), pk_f16(e2, e3) };                      \
            *(uint2*)&Ps[lr * 80 + k4 * 32 + lg * 8] = pk;                      \
        }                                                                       \
        f16x8 pf = *(const f16x8*)&Ps[lr * 80 + lg * 16];                       \
        /* O += P * V */                                                        \
        __builtin_amdgcn_s_setprio(1);                                          \
        _Pragma("unroll")                                                       \
        for (int dt = 0; dt < 4; ++dt) {                                        \
            const int vrow_ = dt * 16 + lr;                                     \
            f16x8 vf = *(const f16x8*)&Vlds[BUF][vrow_ * 64                     \
                            + (((lg ^ (lr & 3))) << 4)];                        \
            o_acc[dt] = mfma16h(pf, vf, o_acc[dt]);                             \
        }                                                                       \
        __builtin_amdgcn_s_setprio(0);                                          \
    }

    STAGE(0, 0);
    STAGE(1, 1);

    for (int it = 0; it < NT_ / 2; ++it) {
        const int t0 = 2 * it;
        // even tile -> buf 0. Outstanding: tiles t0, t0+1 (16 loads) -> wait 8.
        asm volatile("s_waitcnt vmcnt(8)" ::: "memory");
        COMPUTE(0);
        if (t0 + 2 < NT_) STAGE(0, t0 + 2);
        // odd tile -> buf 1.
        if (it == NT_ / 2 - 1) {
            asm volatile("s_waitcnt vmcnt(0)" ::: "memory");
        } else {
            asm volatile("s_waitcnt vmcnt(8)" ::: "memory");
        }
        COMPUTE(1);
        if (t0 + 3 < NT_) STAGE(1, t0 + 3);
    }

    // ---- finalize: reduce l across the 4 lane-copies, divide, store fp32
    float lt = lrun;
    lt += __shfl_xor(lt, 16);
    lt += __shfl_xor(lt, 32);
    #pragma unroll
    for (int r2 = 0; r2 < 4; ++r2) {
        const float inv = 1.0f / __shfl(lt, 4 * lg + r2);
        const int q = q0 + 4 * lg + r2;
        float* yp = Yg + ((size_t)b * HW_ + q) * CI_ + lr;
        #pragma unroll
        for (int dt = 0; dt < 4; ++dt)
            yp[dt * 16] = o_acc[dt][r2] * inv;
    }
#undef STAGE
#undef COMPUTE
}

// ---------------------------------------------------------------------------
// Kernel 4: 1x1 conv back to 128 channels (fp32).
// ---------------------------------------------------------------------------
__global__ __launch_bounds__(256) void conv2_kernel(
    const float* __restrict__ Yg, const float* __restrict__ wW,
    const float* __restrict__ bW, float* __restrict__ Zg)
{
    __shared__ float ys[CI_ * 68];
    __shared__ float ws2[CI_ * 132];
    const int t  = threadIdx.x;
    const int b  = blockIdx.y;
    const int n0 = blockIdx.x * 64;

    const float* ybase = Yg + ((size_t)b * HW_ + n0) * CI_;
    for (int j = t; j < 64 * CI_; j += 256)
        ys[(j & 63) * 68 + (j >> 6)] = ybase[j];
    for (int j = t; j < C_ * CI_; j += 256)
        ws2[(j & 63) * 132 + (j >> 6)] = wW[j];
    __syncthreads();

    const int tp = (t & 15) * 4;
    const int to = (t >> 4) * 8;
    float acc[4][8] = {};
    #pragma unroll 2
    for (int ci = 0; ci < CI_; ++ci) {
        const float4 yv  = *(const float4*)&ys[ci * 68 + tp];
        const float4 wv0 = *(const float4*)&ws2[ci * 132 + to];
        const float4 wv1 = *(const float4*)&ws2[ci * 132 + to + 4];
        const float ya[4] = {yv.x, yv.y, yv.z, yv.w};
        const float wa[8] = {wv0.x, wv0.y, wv0.z, wv0.w, wv1.x, wv1.y, wv1.z, wv1.w};
        #pragma unroll
        for (int i = 0; i < 4; ++i)
            #pragma unroll
            for (int j = 0; j < 8; ++j)
                acc[i][j] += ya[i] * wa[j];
    }
    #pragma unroll
    for (int j = 0; j < 8; ++j) {
        const int o = to + j;
        const float bb = bW[o];
        float* zp = Zg + ((size_t)b * C_ + o) * HW_ + n0 + tp;
        float4 v = { acc[0][j] + bb, acc[1][j] + bb, acc[2][j] + bb, acc[3][j] + bb };
        *(float4*)zp = v;
    }
}

// ---------------------------------------------------------------------------
// Kernel 5: GroupNorm stats (deterministic).
// ---------------------------------------------------------------------------
__global__ __launch_bounds__(256) void stats_kernel(
    const float* __restrict__ Zg, float* __restrict__ stats)
{
    const int t  = threadIdx.x;
    const int gr = blockIdx.x;
    const int b  = blockIdx.y;
    const float4* zp = (const float4*)(Zg + ((size_t)b * C_ + gr * 4) * HW_);
    float s = 0.f, ss = 0.f;
    for (int i = t; i < HW_; i += 256) {
        const float4 v = zp[i];
        s  += v.x + v.y + v.z + v.w;
        ss += v.x*v.x + v.y*v.y + v.z*v.z + v.w*v.w;
    }
    __shared__ float rs[256], rq[256];
    rs[t] = s; rq[t] = ss;
    __syncthreads();
    for (int off = 128; off > 0; off >>= 1) {
        if (t < off) { rs[t] += rs[t + off]; rq[t] += rq[t + off]; }
        __syncthreads();
    }
    if (t == 0) {
        const float invn = 1.0f / (4 * HW_);
        const float mean = rs[0] * invn;
        const float var  = rq[0] * invn - mean * mean;
        stats[((size_t)b * GROUPS_ + gr) * 2 + 0] = mean;
        stats[((size_t)b * GROUPS_ + gr) * 2 + 1] = rsqrtf(var + EPS_);
    }
}

// ---------------------------------------------------------------------------
// Kernel 6: normalize + affine + residual.
// ---------------------------------------------------------------------------
__global__ __launch_bounds__(256) void final_kernel(
    const float* __restrict__ Zg, const float* __restrict__ xg,
    const float* __restrict__ stats, const float* __restrict__ gnw,
    const float* __restrict__ gnb, float* __restrict__ out)
{
    const size_t i4  = (size_t)blockIdx.x * 256 + threadIdx.x;
    const size_t idx = i4 * 4;
    const int bc = (int)(i4 / (HW_ / 4));
    const int c  = bc & 127;
    const int b  = bc >> 7;
    const int g  = c >> 2;
    const float mean = stats[((size_t)b * GROUPS_ + g) * 2 + 0];
    const float rstd = stats[((size_t)b * GROUPS_ + g) * 2 + 1];
    const float sc = rstd * gnw[c];
    const float sh = gnb[c] - mean * sc;
    const float4 z  = *(const float4*)(Zg + idx);
    const float4 xv = *(const float4*)(xg + idx);
    float4 o;
    o.x = z.x * sc + sh + xv.x;
    o.y = z.y * sc + sh + xv.y;
    o.z = z.z * sc + sh + xv.z;
    o.w = z.w * sc + sh + xv.w;
    *(float4*)(out + idx) = o;
}

// ---------------------------------------------------------------------------
extern "C" void kernel_launch(void* const* d_in, const int* in_sizes, int n_in,
                              void* d_out, int out_size, void* d_ws, size_t ws_size,
                              hipStream_t stream)
{
    const float* x       = (const float*)d_in[0];
    const float* w_theta = (const float*)d_in[1];
    const float* b_theta = (const float*)d_in[2];
    const float* w_phi   = (const float*)d_in[3];
    const float* b_phi   = (const float*)d_in[4];
    const float* w_g     = (const float*)d_in[5];
    const float* b_g     = (const float*)d_in[6];
    const float* w_W     = (const float*)d_in[7];
    const float* b_W     = (const float*)d_in[8];
    const float* gn_w    = (const float*)d_in[9];
    const float* gn_b    = (const float*)d_in[10];
    float* out = (float*)d_out;
    char* wsb  = (char*)d_ws;

    // workspace layout (bytes)
    unsigned short* Q    = (unsigned short*)(wsb);             //  4,718,592
    unsigned short* K    = (unsigned short*)(wsb +  4718592);  //  1,179,648
    unsigned short* Vt   = (unsigned short*)(wsb +  5898240);  //  1,179,648
    unsigned short* phiF = (unsigned short*)(wsb +  7077888);  //  4,718,592
    unsigned short* gF   = (unsigned short*)(wsb + 11796480);  //  4,718,592
    float* Y             = (float*)(wsb +  7077888);           //  9,437,184 (aliases phiF+gF, dead after pool)
    float* Z             = (float*)(wsb + 16515072);           // 18,874,368
    float* stats         = (float*)(wsb + 35389440);           //  1 KB

    proj_kernel <<<dim3(HW_ / 32, B_, 3), 256, 0, stream>>>(
        x, w_theta, b_theta, w_phi, b_phi, w_g, b_g, Q, phiF, gF);
    pool_kernel <<<dim3(NP_ * CI_ / 256, B_, 2), 256, 0, stream>>>(phiF, gF, K, Vt);
    attn_kernel <<<dim3(HW_ / 16, B_), 64, 0, stream>>>(Q, K, Vt, Y);
    conv2_kernel<<<dim3(HW_ / 64, B_), 256, 0, stream>>>(Y, w_W, b_W, Z);
    stats_kernel<<<dim3(GROUPS_, B_), 256, 0, stream>>>(Z, stats);
    final_kernel<<<dim3((B_ * C_ * HW_) / 1024, 1), 256, 0, stream>>>(
        Z, x, stats, gn_w, gn_b, out);
}

// Round 10
// 166.801 us; speedup vs baseline: 1.0109x; 1.0109x over previous
//
#include <hip/hip_runtime.h>
#include <math.h>

#define B_ 4
#define C_ 128
#define CI_ 64
#define H_ 96
#define W_ 96
#define HW_ (H_*W_)      // 9216
#define NP_ 2304         // 48*48
#define GROUPS_ 32
#define EPS_ 1e-5f
#define KVT_ 32          // KV tile rows
#define NT_ (NP_/KVT_)   // 72 tiles

typedef _Float16 f16x8 __attribute__((ext_vector_type(8)));
typedef _Float16 f16x2 __attribute__((ext_vector_type(2)));
typedef __attribute__((ext_vector_type(4))) float f32x4;

__device__ inline f32x4 mfma16h(f16x8 a, f16x8 b, f32x4 c) {
    return __builtin_amdgcn_mfma_f32_16x16x32_f16(a, b, c, 0, 0, 0);
}
__device__ inline float h2f(unsigned short s) {
    return (float)__builtin_bit_cast(_Float16, s);
}
__device__ inline unsigned pk_f16(float a, float b) {     // pack 2 f32 -> 2 f16 (RTZ)
    return __builtin_bit_cast(unsigned, __builtin_amdgcn_cvt_pkrtz(a, b));
}
// global -> LDS direct DMA, 16B/lane. LDS dest = wave-uniform base + lane*16.
__device__ inline void gload_lds16(const void* g, void* l) {
    __builtin_amdgcn_global_load_lds(
        (const __attribute__((address_space(1))) void*)reinterpret_cast<uintptr_t>(g),
        (__attribute__((address_space(3))) void*)(unsigned)reinterpret_cast<uintptr_t>(l),
        16, 0, 0);
}

// ---------------------------------------------------------------------------
// Kernel 1: fused 3-way 1x1 conv projections -> fp16 [b][n][ci]
// ---------------------------------------------------------------------------
__global__ __launch_bounds__(256) void proj_kernel(
    const float* __restrict__ x,
    const float* __restrict__ w_theta, const float* __restrict__ b_theta,
    const float* __restrict__ w_phi,   const float* __restrict__ b_phi,
    const float* __restrict__ w_g,     const float* __restrict__ b_g,
    unsigned short* __restrict__ Qo, unsigned short* __restrict__ phiF,
    unsigned short* __restrict__ gF)
{
    __shared__ float xs[C_ * 32];   // xs[c*32 + pix]
    __shared__ float ws[C_ * 68];   // ws[c*68 + ci]
    const int t    = threadIdx.x;
    const int tile = blockIdx.x;
    const int b    = blockIdx.y;
    const int mat  = blockIdx.z;
    const float* wsel = (mat == 0) ? w_theta : (mat == 1) ? w_phi : w_g;
    const float* bsel = (mat == 0) ? b_theta : (mat == 1) ? b_phi : b_g;
    unsigned short* osel = (mat == 0) ? Qo : (mat == 1) ? phiF : gF;
    const int n0 = tile * 32;

    {
        const int pix = t & 31;
        const int c0  = t >> 5;
        const float* xb = x + (size_t)b * C_ * HW_ + n0 + pix;
        for (int c = c0; c < C_; c += 8)
            xs[c * 32 + pix] = xb[(size_t)c * HW_];
    }
    for (int j = t; j < CI_ * C_; j += 256)
        ws[(j & 127) * 68 + (j >> 7)] = wsel[j];
    __syncthreads();

    const int tp = (t & 7) * 4;
    const int tc = (t >> 3) * 2;
    float acc[4][2] = {};
    #pragma unroll 4
    for (int c = 0; c < C_; ++c) {
        const float4 xv = *(const float4*)&xs[c * 32 + tp];
        const float2 wv = *(const float2*)&ws[c * 68 + tc];
        const float xa[4] = {xv.x, xv.y, xv.z, xv.w};
        #pragma unroll
        for (int i = 0; i < 4; ++i) {
            acc[i][0] += xa[i] * wv.x;
            acc[i][1] += xa[i] * wv.y;
        }
    }
    const float2 bb = *(const float2*)&bsel[tc];
    #pragma unroll
    for (int i = 0; i < 4; ++i) {
        f16x2 hv = { (_Float16)(acc[i][0] + bb.x), (_Float16)(acc[i][1] + bb.y) };
        *(f16x2*)&osel[((size_t)b * HW_ + n0 + tp + i) * CI_ + tc] = hv;
    }
}

// ---------------------------------------------------------------------------
// Kernel 2: 2x2 maxpool (fp16 in/out, exact). K stays [b][m][ci].
// V -> [b][ci][m'] TRANSPOSED with per-32-group column permutation pi so that
// PV's B-fragment k-order matches the in-register P k-order (no P repack):
//   stored col c holds orig k = 16*((c&7)>>2) + 4*(c>>3) + (c&3)  (within group)
//   inverse (write side): m' = (m&~31) | (8*((m>>2)&3) + 4*((m>>4)&1) + (m&3))
// ---------------------------------------------------------------------------
__global__ __launch_bounds__(256) void pool_kernel(
    const unsigned short* __restrict__ phiF, const unsigned short* __restrict__ gF,
    unsigned short* __restrict__ Ko, unsigned short* __restrict__ Vt)
{
    const int t   = threadIdx.x;
    const int b   = blockIdx.y;
    const int mat = blockIdx.z;                 // 0 -> K, 1 -> V^T(permuted)
    const int idx = blockIdx.x * 256 + t;       // 0..147455
    int m, ci;
    if (mat == 0) { m = idx >> 6; ci = idx & 63; }
    else          { ci = idx / NP_; m = idx - ci * NP_; }
    const int ph = m / 48, pw = m % 48;
    const int n00 = (ph * 2) * W_ + pw * 2;
    const unsigned short* src = mat ? gF : phiF;
    const unsigned short* p = src + ((size_t)b * HW_ + n00) * CI_ + ci;
    float v = fmaxf(fmaxf(h2f(p[0]), h2f(p[CI_])),
                    fmaxf(h2f(p[(size_t)W_ * CI_]), h2f(p[(size_t)(W_ + 1) * CI_])));
    unsigned short r = __builtin_bit_cast(unsigned short, (_Float16)v); // exact
    if (mat == 0) {
        Ko[((size_t)b * NP_ + m) * CI_ + ci] = r;
    } else {
        const int ms = (m & ~31) | (8 * ((m >> 2) & 3) + 4 * ((m >> 4) & 1) + (m & 3));
        Vt[((size_t)b * CI_ + ci) * NP_ + ms] = r;
    }
}

// ---------------------------------------------------------------------------
// Kernel 3: fp16 MFMA flash attention — single-wave blocks, barrier-free,
// and NO P->LDS roundtrip: P feeds PV directly from registers (V columns are
// pre-permuted by pool_kernel to match the lane-local k-order).
// 16 q-rows/wave, 2304 waves; LDS 16 KB -> 10 blocks/CU ceiling, grid 9/CU.
// K/V double-buffered via global_load_lds, counted vmcnt(8) (T4).
// ---------------------------------------------------------------------------
__global__ __launch_bounds__(64) void attn_kernel(
    const unsigned short* __restrict__ Qg, const unsigned short* __restrict__ Kg,
    const unsigned short* __restrict__ Vt, float* __restrict__ Yg)
{
    __shared__ unsigned char Klds[2][4096];   // [buf][32 k-rows x 128B]
    __shared__ unsigned char Vlds[2][4096];   // [buf][64 d-rows x  64B]

    const int lane = threadIdx.x;
    const int lr   = lane & 15;
    const int lg   = lane >> 4;
    const int b    = blockIdx.y;
    const int q0   = blockIdx.x * 16;

    // staging lane constants (inverse-swizzled global chunk per rule 21)
    const int krow = lane >> 3;                       // 0..7 (K: 8 rows/load)
    const int kchk = (lane & 7) ^ krow;               // K source 16B-chunk
    const int vrow = lane >> 2;                       // 0..15 (V: 16 rows/load)
    const int vchk = (lane & 3) ^ (vrow & 3);         // V source 16B-chunk

    const unsigned short* Kb = Kg + (size_t)b * NP_ * CI_;
    const unsigned short* Vb = Vt + (size_t)b * CI_ * NP_;

    // Q fragments: u in {0,1} d-halves
    f16x8 qf[2];
    #pragma unroll
    for (int u = 0; u < 2; ++u)
        qf[u] = *(const f16x8*)(Qg + ((size_t)b * HW_ + q0 + lr) * CI_ + u * 32 + lg * 8);

    f32x4 o_acc[4];
    #pragma unroll
    for (int dt = 0; dt < 4; ++dt) o_acc[dt] = (f32x4){0.f, 0.f, 0.f, 0.f};
    float mrun = -1e30f, lrun = 0.f;    // lrun = per-lane partial (reduced at end)

#define STAGE(BUF, TT)                                                          \
    {                                                                           \
        const int kv0_ = (TT) * KVT_;                                           \
        _Pragma("unroll")                                                       \
        for (int i = 0; i < 4; ++i)                                             \
            gload_lds16(Kb + (size_t)(kv0_ + 8 * i + krow) * CI_ + kchk * 8,    \
                        &Klds[BUF][i * 1024]);                                  \
        _Pragma("unroll")                                                       \
        for (int i = 0; i < 4; ++i)                                             \
            gload_lds16(Vb + (size_t)(16 * i + vrow) * NP_ + kv0_ + vchk * 8,   \
                        &Vlds[BUF][i * 1024]);                                  \
    }

#define COMPUTE(BUF)                                                            \
    {                                                                           \
        /* K fragments: kf[u][k4] = K[k4*16+lr][u*32 + lg*8 ..], swizzled */    \
        f16x8 kf[2][2];                                                         \
        _Pragma("unroll")                                                       \
        for (int u = 0; u < 2; ++u)                                             \
            _Pragma("unroll")                                                   \
            for (int k4 = 0; k4 < 2; ++k4)                                      \
                kf[u][k4] = *(const f16x8*)&Klds[BUF][(k4 * 16 + lr) * 128      \
                                + (((4 * u + lg) ^ (lr & 7)) << 4)];            \
        f32x4 s[2];                                                             \
        s[0] = (f32x4){0.f, 0.f, 0.f, 0.f};                                     \
        s[1] = (f32x4){0.f, 0.f, 0.f, 0.f};                                     \
        __builtin_amdgcn_s_setprio(1);                                          \
        _Pragma("unroll")                                                       \
        for (int u = 0; u < 2; ++u) {                                           \
            s[0] = mfma16h(kf[u][0], qf[u], s[0]);                              \
            s[1] = mfma16h(kf[u][1], qf[u], s[1]);                              \
        }                                                                       \
        __builtin_amdgcn_s_setprio(0);                                          \
        /* vote-based defer-max: no cross-lane in common path */                \
        float tmax = fmaxf(fmaxf(fmaxf(s[0][0], s[0][1]),                       \
                                 fmaxf(s[0][2], s[0][3])),                      \
                           fmaxf(fmaxf(s[1][0], s[1][1]),                       \
                                 fmaxf(s[1][2], s[1][3])));                     \
        if (!__all(tmax <= mrun + 8.0f)) {                                      \
            tmax = fmaxf(tmax, __shfl_xor(tmax, 16));                           \
            tmax = fmaxf(tmax, __shfl_xor(tmax, 32));                           \
            const float mnew = fmaxf(mrun, tmax);                               \
            const float sc = __expf(mrun - mnew);                               \
            lrun *= sc;                                                         \
            _Pragma("unroll")                                                   \
            for (int r2 = 0; r2 < 4; ++r2) {                                    \
                const float scb = __shfl(sc, 4 * lg + r2);                      \
                _Pragma("unroll")                                               \
                for (int dt = 0; dt < 4; ++dt) o_acc[dt][r2] *= scb;            \
            }                                                                   \
            mrun = mnew;                                                        \
        }                                                                       \
        /* P = exp(S - m): pack IN REGISTERS in lane-local k-order */           \
        const float e00 = __expf(s[0][0] - mrun);                               \
        const float e01 = __expf(s[0][1] - mrun);                               \
        const float e02 = __expf(s[0][2] - mrun);                               \
        const float e03 = __expf(s[0][3] - mrun);                               \
        const float e10 = __expf(s[1][0] - mrun);                               \
        const float e11 = __expf(s[1][1] - mrun);                               \
        const float e12 = __expf(s[1][2] - mrun);                               \
        const float e13 = __expf(s[1][3] - mrun);                               \
        lrun += ((e00 + e01) + (e02 + e03)) + ((e10 + e11) + (e12 + e13));      \
        uint4 pku = { pk_f16(e00, e01), pk_f16(e02, e03),                       \
                      pk_f16(e10, e11), pk_f16(e12, e13) };                     \
        f16x8 pf = __builtin_bit_cast(f16x8, pku);                              \
        /* O += P * V  (V columns pre-permuted to this k-order) */              \
        __builtin_amdgcn_s_setprio(1);                                          \
        _Pragma("unroll")                                                       \
        for (int dt = 0; dt < 4; ++dt) {                                        \
            const int vrow_ = dt * 16 + lr;                                     \
            f16x8 vf = *(const f16x8*)&Vlds[BUF][vrow_ * 64                     \
                            + (((lg ^ (lr & 3))) << 4)];                        \
            o_acc[dt] = mfma16h(pf, vf, o_acc[dt]);                             \
        }                                                                       \
        __builtin_amdgcn_s_setprio(0);                                          \
    }

    STAGE(0, 0);
    STAGE(1, 1);

    for (int it = 0; it < NT_ / 2; ++it) {
        const int t0 = 2 * it;
        // even tile -> buf 0. Outstanding: tiles t0, t0+1 (16 loads) -> wait 8.
        asm volatile("s_waitcnt vmcnt(8)" ::: "memory");
        COMPUTE(0);
        if (t0 + 2 < NT_) STAGE(0, t0 + 2);
        // odd tile -> buf 1.
        if (it == NT_ / 2 - 1) {
            asm volatile("s_waitcnt vmcnt(0)" ::: "memory");
        } else {
            asm volatile("s_waitcnt vmcnt(8)" ::: "memory");
        }
        COMPUTE(1);
        if (t0 + 3 < NT_) STAGE(1, t0 + 3);
    }

    // ---- finalize: reduce l across the 4 lane-copies, divide, store fp32
    float lt = lrun;
    lt += __shfl_xor(lt, 16);
    lt += __shfl_xor(lt, 32);
    #pragma unroll
    for (int r2 = 0; r2 < 4; ++r2) {
        const float inv = 1.0f / __shfl(lt, 4 * lg + r2);
        const int q = q0 + 4 * lg + r2;
        float* yp = Yg + ((size_t)b * HW_ + q) * CI_ + lr;
        #pragma unroll
        for (int dt = 0; dt < 4; ++dt)
            yp[dt * 16] = o_acc[dt][r2] * inv;
    }
#undef STAGE
#undef COMPUTE
}

// ---------------------------------------------------------------------------
// Kernel 4: 1x1 conv back to 128 channels (fp32).
// ---------------------------------------------------------------------------
__global__ __launch_bounds__(256) void conv2_kernel(
    const float* __restrict__ Yg, const float* __restrict__ wW,
    const float* __restrict__ bW, float* __restrict__ Zg)
{
    __shared__ float ys[CI_ * 68];
    __shared__ float ws2[CI_ * 132];
    const int t  = threadIdx.x;
    const int b  = blockIdx.y;
    const int n0 = blockIdx.x * 64;

    const float* ybase = Yg + ((size_t)b * HW_ + n0) * CI_;
    for (int j = t; j < 64 * CI_; j += 256)
        ys[(j & 63) * 68 + (j >> 6)] = ybase[j];
    for (int j = t; j < C_ * CI_; j += 256)
        ws2[(j & 63) * 132 + (j >> 6)] = wW[j];
    __syncthreads();

    const int tp = (t & 15) * 4;
    const int to = (t >> 4) * 8;
    float acc[4][8] = {};
    #pragma unroll 2
    for (int ci = 0; ci < CI_; ++ci) {
        const float4 yv  = *(const float4*)&ys[ci * 68 + tp];
        const float4 wv0 = *(const float4*)&ws2[ci * 132 + to];
        const float4 wv1 = *(const float4*)&ws2[ci * 132 + to + 4];
        const float ya[4] = {yv.x, yv.y, yv.z, yv.w};
        const float wa[8] = {wv0.x, wv0.y, wv0.z, wv0.w, wv1.x, wv1.y, wv1.z, wv1.w};
        #pragma unroll
        for (int i = 0; i < 4; ++i)
            #pragma unroll
            for (int j = 0; j < 8; ++j)
                acc[i][j] += ya[i] * wa[j];
    }
    #pragma unroll
    for (int j = 0; j < 8; ++j) {
        const int o = to + j;
        const float bb = bW[o];
        float* zp = Zg + ((size_t)b * C_ + o) * HW_ + n0 + tp;
        float4 v = { acc[0][j] + bb, acc[1][j] + bb, acc[2][j] + bb, acc[3][j] + bb };
        *(float4*)zp = v;
    }
}

// ---------------------------------------------------------------------------
// Kernel 5: GroupNorm stats (deterministic).
// ---------------------------------------------------------------------------
__global__ __launch_bounds__(256) void stats_kernel(
    const float* __restrict__ Zg, float* __restrict__ stats)
{
    const int t  = threadIdx.x;
    const int gr = blockIdx.x;
    const int b  = blockIdx.y;
    const float4* zp = (const float4*)(Zg + ((size_t)b * C_ + gr * 4) * HW_);
    float s = 0.f, ss = 0.f;
    for (int i = t; i < HW_; i += 256) {
        const float4 v = zp[i];
        s  += v.x + v.y + v.z + v.w;
        ss += v.x*v.x + v.y*v.y + v.z*v.z + v.w*v.w;
    }
    __shared__ float rs[256], rq[256];
    rs[t] = s; rq[t] = ss;
    __syncthreads();
    for (int off = 128; off > 0; off >>= 1) {
        if (t < off) { rs[t] += rs[t + off]; rq[t] += rq[t + off]; }
        __syncthreads();
    }
    if (t == 0) {
        const float invn = 1.0f / (4 * HW_);
        const float mean = rs[0] * invn;
        const float var  = rq[0] * invn - mean * mean;
        stats[((size_t)b * GROUPS_ + gr) * 2 + 0] = mean;
        stats[((size_t)b * GROUPS_ + gr) * 2 + 1] = rsqrtf(var + EPS_);
    }
}

// ---------------------------------------------------------------------------
// Kernel 6: normalize + affine + residual.
// ---------------------------------------------------------------------------
__global__ __launch_bounds__(256) void final_kernel(
    const float* __restrict__ Zg, const float* __restrict__ xg,
    const float* __restrict__ stats, const float* __restrict__ gnw,
    const float* __restrict__ gnb, float* __restrict__ out)
{
    const size_t i4  = (size_t)blockIdx.x * 256 + threadIdx.x;
    const size_t idx = i4 * 4;
    const int bc = (int)(i4 / (HW_ / 4));
    const int c  = bc & 127;
    const int b  = bc >> 7;
    const int g  = c >> 2;
    const float mean = stats[((size_t)b * GROUPS_ + g) * 2 + 0];
    const float rstd = stats[((size_t)b * GROUPS_ + g) * 2 + 1];
    const float sc = rstd * gnw[c];
    const float sh = gnb[c] - mean * sc;
    const float4 z  = *(const float4*)(Zg + idx);
    const float4 xv = *(const float4*)(xg + idx);
    float4 o;
    o.x = z.x * sc + sh + xv.x;
    o.y = z.y * sc + sh + xv.y;
    o.z = z.z * sc + sh + xv.z;
    o.w = z.w * sc + sh + xv.w;
    *(float4*)(out + idx) = o;
}

// ---------------------------------------------------------------------------
extern "C" void kernel_launch(void* const* d_in, const int* in_sizes, int n_in,
                              void* d_out, int out_size, void* d_ws, size_t ws_size,
                              hipStream_t stream)
{
    const float* x       = (const float*)d_in[0];
    const float* w_theta = (const float*)d_in[1];
    const float* b_theta = (const float*)d_in[2];
    const float* w_phi   = (const float*)d_in[3];
    const float* b_phi   = (const float*)d_in[4];
    const float* w_g     = (const float*)d_in[5];
    const float* b_g     = (const float*)d_in[6];
    const float* w_W     = (const float*)d_in[7];
    const float* b_W     = (const float*)d_in[8];
    const float* gn_w    = (const float*)d_in[9];
    const float* gn_b    = (const float*)d_in[10];
    float* out = (float*)d_out;
    char* wsb  = (char*)d_ws;

    // workspace layout (bytes)
    unsigned short* Q    = (unsigned short*)(wsb);             //  4,718,592
    unsigned short* K    = (unsigned short*)(wsb +  4718592);  //  1,179,648
    unsigned short* Vt   = (unsigned short*)(wsb +  5898240);  //  1,179,648
    unsigned short* phiF = (unsigned short*)(wsb +  7077888);  //  4,718,592
    unsigned short* gF   = (unsigned short*)(wsb + 11796480);  //  4,718,592
    float* Y             = (float*)(wsb +  7077888);           //  9,437,184 (aliases phiF+gF, dead after pool)
    float* Z             = (float*)(wsb + 16515072);           // 18,874,368
    float* stats         = (float*)(wsb + 35389440);           //  1 KB

    proj_kernel <<<dim3(HW_ / 32, B_, 3), 256, 0, stream>>>(
        x, w_theta, b_theta, w_phi, b_phi, w_g, b_g, Q, phiF, gF);
    pool_kernel <<<dim3(NP_ * CI_ / 256, B_, 2), 256, 0, stream>>>(phiF, gF, K, Vt);
    attn_kernel <<<dim3(HW_ / 16, B_), 64, 0, stream>>>(Q, K, Vt, Y);
    conv2_kernel<<<dim3(HW_ / 64, B_), 256, 0, stream>>>(Y, w_W, b_W, Z);
    stats_kernel<<<dim3(GROUPS_, B_), 256, 0, stream>>>(Z, stats);
    final_kernel<<<dim3((B_ * C_ * HW_) / 1024, 1), 256, 0, stream>>>(
        Z, x, stats, gn_w, gn_b, out);
}

// Round 11
// 147.561 us; speedup vs baseline: 1.1427x; 1.1304x over previous
//
#include <hip/hip_runtime.h>
#include <math.h>

#define B_ 4
#define C_ 128
#define CI_ 64
#define H_ 96
#define W_ 96
#define HW_ (H_*W_)      // 9216
#define NP_ 2304         // 48*48
#define GROUPS_ 32
#define EPS_ 1e-5f
#define KVT_ 32          // KV tile rows
#define NT_ (NP_/KVT_)   // 72 tiles

typedef _Float16 f16x8 __attribute__((ext_vector_type(8)));
typedef _Float16 f16x2 __attribute__((ext_vector_type(2)));
typedef __attribute__((ext_vector_type(4))) float f32x4;

__device__ inline f32x4 mfma16h(f16x8 a, f16x8 b, f32x4 c) {
    return __builtin_amdgcn_mfma_f32_16x16x32_f16(a, b, c, 0, 0, 0);
}
__device__ inline float h2f(unsigned short s) {
    return (float)__builtin_bit_cast(_Float16, s);
}
__device__ inline unsigned pk_f16(float a, float b) {     // pack 2 f32 -> 2 f16 (RTZ)
    return __builtin_bit_cast(unsigned, __builtin_amdgcn_cvt_pkrtz(a, b));
}
__device__ inline f16x8 pk8(float v0, float v1, float v2, float v3,
                            float v4, float v5, float v6, float v7) {
    uint4 u = { pk_f16(v0, v1), pk_f16(v2, v3), pk_f16(v4, v5), pk_f16(v6, v7) };
    return __builtin_bit_cast(f16x8, u);
}
// global -> LDS direct DMA, 16B/lane. LDS dest = wave-uniform base + lane*16.
__device__ inline void gload_lds16(const void* g, void* l) {
    __builtin_amdgcn_global_load_lds(
        (const __attribute__((address_space(1))) void*)reinterpret_cast<uintptr_t>(g),
        (__attribute__((address_space(3))) void*)(unsigned)reinterpret_cast<uintptr_t>(l),
        16, 0, 0);
}

// ---------------------------------------------------------------------------
// Kernel 0: cast the 4 weight matrices to fp16 (Whall[32768]).
// [0..8192) w_theta | [8192..16384) w_phi | [16384..24576) w_g | [24576..32768) w_W
// ---------------------------------------------------------------------------
__global__ __launch_bounds__(256) void wprep_kernel(
    const float* __restrict__ w_theta, const float* __restrict__ w_phi,
    const float* __restrict__ w_g,     const float* __restrict__ w_W,
    unsigned short* __restrict__ Whall)
{
    const int idx = blockIdx.x * 256 + threadIdx.x;   // 0..32767
    float v;
    if      (idx <  8192) v = w_theta[idx];
    else if (idx < 16384) v = w_phi[idx - 8192];
    else if (idx < 24576) v = w_g[idx - 16384];
    else                  v = w_W[idx - 24576];
    Whall[idx] = __builtin_bit_cast(unsigned short, (_Float16)v);
}

// ---------------------------------------------------------------------------
// Kernel 1: fused 3-way 1x1 conv projections as fp16 MFMA GEMM.
// Block = 4 waves x 16 px (64 px); grid 144 x 4. All 3 mats per block (x read once).
// A-frag = x^T (strided fp32 loads + cvt, 64B-coalesced); B-frag = fp16 W rows.
// D[px=4lg+r][ci=lr]; epilogue via LDS bounce for 16B fp16 stores.
// ---------------------------------------------------------------------------
__global__ __launch_bounds__(256) void proj_kernel(
    const float* __restrict__ x, const unsigned short* __restrict__ Whall,
    const float* __restrict__ b_theta, const float* __restrict__ b_phi,
    const float* __restrict__ b_g,
    unsigned short* __restrict__ Qo, unsigned short* __restrict__ phiF,
    unsigned short* __restrict__ gF)
{
    __shared__ __align__(16) unsigned short pb[4][16 * 72];   // per-wave bounce

    const int t    = threadIdx.x;
    const int wv   = t >> 6;
    const int lane = t & 63;
    const int lr   = lane & 15;
    const int lg   = lane >> 4;
    const int b    = blockIdx.y;
    const int px0  = blockIdx.x * 64 + wv * 16;

    // ---- A fragments: xa[u] = x^T[px0+lr][u*32 + lg*8 + 0..7]  (fp32 -> fp16)
    const float* xb = x + (size_t)b * C_ * HW_ + px0 + lr;
    f16x8 xa[4];
    #pragma unroll
    for (int u = 0; u < 4; ++u) {
        const float* p = xb + (size_t)(u * 32 + lg * 8) * HW_;
        xa[u] = pk8(p[0], p[(size_t)HW_], p[2 * (size_t)HW_], p[3 * (size_t)HW_],
                    p[4 * (size_t)HW_], p[5 * (size_t)HW_], p[6 * (size_t)HW_],
                    p[7 * (size_t)HW_]);
    }

    #pragma unroll
    for (int mat = 0; mat < 3; ++mat) {
        const unsigned short* Whp = Whall + mat * 8192;
        const float* bsel = (mat == 0) ? b_theta : (mat == 1) ? b_phi : b_g;
        unsigned short* osel = (mat == 0) ? Qo : (mat == 1) ? phiF : gF;

        f32x4 D[4];
        #pragma unroll
        for (int ct = 0; ct < 4; ++ct) D[ct] = (f32x4){0.f, 0.f, 0.f, 0.f};
        #pragma unroll
        for (int u = 0; u < 4; ++u)
            #pragma unroll
            for (int ct = 0; ct < 4; ++ct) {
                f16x8 wb = *(const f16x8*)&Whp[(ct * 16 + lr) * 128 + u * 32 + lg * 8];
                D[ct] = mfma16h(xa[u], wb, D[ct]);
            }

        // bias + bounce to LDS (value at px=4lg+r2, ci=ct*16+lr)
        #pragma unroll
        for (int ct = 0; ct < 4; ++ct) {
            const float bi = bsel[ct * 16 + lr];
            #pragma unroll
            for (int r2 = 0; r2 < 4; ++r2)
                pb[wv][(4 * lg + r2) * 72 + ct * 16 + lr] =
                    __builtin_bit_cast(unsigned short, (_Float16)(D[ct][r2] + bi));
        }
        // coalesced write-out: lane covers px=lane>>2, ci-chunk=(lane&3)*16
        {
            const int px = lane >> 2, ch = lane & 3;
            f16x8 y0 = *(const f16x8*)&pb[wv][px * 72 + ch * 16];
            f16x8 y1 = *(const f16x8*)&pb[wv][px * 72 + ch * 16 + 8];
            unsigned short* op = osel + ((size_t)b * HW_ + px0 + px) * CI_ + ch * 16;
            *(f16x8*)op       = y0;
            *(f16x8*)(op + 8) = y1;
        }
    }
}

// ---------------------------------------------------------------------------
// Kernel 2: 2x2 maxpool (fp16 in/out, exact). K stays [b][m][ci].
// V -> [b][ci][m'] transposed + per-32-group permuted (PV k-order match).
// ---------------------------------------------------------------------------
__global__ __launch_bounds__(256) void pool_kernel(
    const unsigned short* __restrict__ phiF, const unsigned short* __restrict__ gF,
    unsigned short* __restrict__ Ko, unsigned short* __restrict__ Vt)
{
    const int t   = threadIdx.x;
    const int b   = blockIdx.y;
    const int mat = blockIdx.z;                 // 0 -> K, 1 -> V^T(permuted)
    const int idx = blockIdx.x * 256 + t;       // 0..147455
    int m, ci;
    if (mat == 0) { m = idx >> 6; ci = idx & 63; }
    else          { ci = idx / NP_; m = idx - ci * NP_; }
    const int ph = m / 48, pw = m % 48;
    const int n00 = (ph * 2) * W_ + pw * 2;
    const unsigned short* src = mat ? gF : phiF;
    const unsigned short* p = src + ((size_t)b * HW_ + n00) * CI_ + ci;
    float v = fmaxf(fmaxf(h2f(p[0]), h2f(p[CI_])),
                    fmaxf(h2f(p[(size_t)W_ * CI_]), h2f(p[(size_t)(W_ + 1) * CI_])));
    unsigned short r = __builtin_bit_cast(unsigned short, (_Float16)v); // exact
    if (mat == 0) {
        Ko[((size_t)b * NP_ + m) * CI_ + ci] = r;
    } else {
        const int ms = (m & ~31) | (8 * ((m >> 2) & 3) + 4 * ((m >> 4) & 1) + (m & 3));
        Vt[((size_t)b * CI_ + ci) * NP_ + ms] = r;
    }
}

// ---------------------------------------------------------------------------
// Kernel 3: fp16 MFMA flash attention (R10 structure, unchanged main loop).
// Output Y now stored as fp16 via LDS bounce (feeds conv2 MFMA directly).
// ---------------------------------------------------------------------------
__global__ __launch_bounds__(64) void attn_kernel(
    const unsigned short* __restrict__ Qg, const unsigned short* __restrict__ Kg,
    const unsigned short* __restrict__ Vt, unsigned short* __restrict__ Yh)
{
    __shared__ unsigned char Klds[2][4096];   // [buf][32 k-rows x 128B]
    __shared__ unsigned char Vlds[2][4096];   // [buf][64 d-rows x  64B]

    const int lane = threadIdx.x;
    const int lr   = lane & 15;
    const int lg   = lane >> 4;
    const int b    = blockIdx.y;
    const int q0   = blockIdx.x * 16;

    const int krow = lane >> 3;                       // 0..7 (K: 8 rows/load)
    const int kchk = (lane & 7) ^ krow;               // K source 16B-chunk
    const int vrow = lane >> 2;                       // 0..15 (V: 16 rows/load)
    const int vchk = (lane & 3) ^ (vrow & 3);         // V source 16B-chunk

    const unsigned short* Kb = Kg + (size_t)b * NP_ * CI_;
    const unsigned short* Vb = Vt + (size_t)b * CI_ * NP_;

    f16x8 qf[2];
    #pragma unroll
    for (int u = 0; u < 2; ++u)
        qf[u] = *(const f16x8*)(Qg + ((size_t)b * HW_ + q0 + lr) * CI_ + u * 32 + lg * 8);

    f32x4 o_acc[4];
    #pragma unroll
    for (int dt = 0; dt < 4; ++dt) o_acc[dt] = (f32x4){0.f, 0.f, 0.f, 0.f};
    float mrun = -1e30f, lrun = 0.f;

#define STAGE(BUF, TT)                                                          \
    {                                                                           \
        const int kv0_ = (TT) * KVT_;                                           \
        _Pragma("unroll")                                                       \
        for (int i = 0; i < 4; ++i)                                             \
            gload_lds16(Kb + (size_t)(kv0_ + 8 * i + krow) * CI_ + kchk * 8,    \
                        &Klds[BUF][i * 1024]);                                  \
        _Pragma("unroll")                                                       \
        for (int i = 0; i < 4; ++i)                                             \
            gload_lds16(Vb + (size_t)(16 * i + vrow) * NP_ + kv0_ + vchk * 8,   \
                        &Vlds[BUF][i * 1024]);                                  \
    }

#define COMPUTE(BUF)                                                            \
    {                                                                           \
        f16x8 kf[2][2];                                                         \
        _Pragma("unroll")                                                       \
        for (int u = 0; u < 2; ++u)                                             \
            _Pragma("unroll")                                                   \
            for (int k4 = 0; k4 < 2; ++k4)                                      \
                kf[u][k4] = *(const f16x8*)&Klds[BUF][(k4 * 16 + lr) * 128      \
                                + (((4 * u + lg) ^ (lr & 7)) << 4)];            \
        f32x4 s[2];                                                             \
        s[0] = (f32x4){0.f, 0.f, 0.f, 0.f};                                     \
        s[1] = (f32x4){0.f, 0.f, 0.f, 0.f};                                     \
        __builtin_amdgcn_s_setprio(1);                                          \
        _Pragma("unroll")                                                       \
        for (int u = 0; u < 2; ++u) {                                           \
            s[0] = mfma16h(kf[u][0], qf[u], s[0]);                              \
            s[1] = mfma16h(kf[u][1], qf[u], s[1]);                              \
        }                                                                       \
        __builtin_amdgcn_s_setprio(0);                                          \
        float tmax = fmaxf(fmaxf(fmaxf(s[0][0], s[0][1]),                       \
                                 fmaxf(s[0][2], s[0][3])),                      \
                           fmaxf(fmaxf(s[1][0], s[1][1]),                       \
                                 fmaxf(s[1][2], s[1][3])));                     \
        if (!__all(tmax <= mrun + 8.0f)) {                                      \
            tmax = fmaxf(tmax, __shfl_xor(tmax, 16));                           \
            tmax = fmaxf(tmax, __shfl_xor(tmax, 32));                           \
            const float mnew = fmaxf(mrun, tmax);                               \
            const float sc = __expf(mrun - mnew);                               \
            lrun *= sc;                                                         \
            _Pragma("unroll")                                                   \
            for (int r2 = 0; r2 < 4; ++r2) {                                    \
                const float scb = __shfl(sc, 4 * lg + r2);                      \
                _Pragma("unroll")                                               \
                for (int dt = 0; dt < 4; ++dt) o_acc[dt][r2] *= scb;            \
            }                                                                   \
            mrun = mnew;                                                        \
        }                                                                       \
        const float e00 = __expf(s[0][0] - mrun);                               \
        const float e01 = __expf(s[0][1] - mrun);                               \
        const float e02 = __expf(s[0][2] - mrun);                               \
        const float e03 = __expf(s[0][3] - mrun);                               \
        const float e10 = __expf(s[1][0] - mrun);                               \
        const float e11 = __expf(s[1][1] - mrun);                               \
        const float e12 = __expf(s[1][2] - mrun);                               \
        const float e13 = __expf(s[1][3] - mrun);                               \
        lrun += ((e00 + e01) + (e02 + e03)) + ((e10 + e11) + (e12 + e13));      \
        f16x8 pf = pk8(e00, e01, e02, e03, e10, e11, e12, e13);                 \
        __builtin_amdgcn_s_setprio(1);                                          \
        _Pragma("unroll")                                                       \
        for (int dt = 0; dt < 4; ++dt) {                                        \
            const int vrow_ = dt * 16 + lr;                                     \
            f16x8 vf = *(const f16x8*)&Vlds[BUF][vrow_ * 64                     \
                            + (((lg ^ (lr & 3))) << 4)];                        \
            o_acc[dt] = mfma16h(pf, vf, o_acc[dt]);                             \
        }                                                                       \
        __builtin_amdgcn_s_setprio(0);                                          \
    }

    STAGE(0, 0);
    STAGE(1, 1);

    for (int it = 0; it < NT_ / 2; ++it) {
        const int t0 = 2 * it;
        asm volatile("s_waitcnt vmcnt(8)" ::: "memory");
        COMPUTE(0);
        if (t0 + 2 < NT_) STAGE(0, t0 + 2);
        if (it == NT_ / 2 - 1) {
            asm volatile("s_waitcnt vmcnt(0)" ::: "memory");
        } else {
            asm volatile("s_waitcnt vmcnt(8)" ::: "memory");
        }
        COMPUTE(1);
        if (t0 + 3 < NT_) STAGE(1, t0 + 3);
    }

    // ---- finalize: reduce l, scale, bounce through (dead) Klds, store fp16
    float lt = lrun;
    lt += __shfl_xor(lt, 16);
    lt += __shfl_xor(lt, 32);
    unsigned short* yb = (unsigned short*)&Klds[0][0];   // [16][72] halves
    #pragma unroll
    for (int r2 = 0; r2 < 4; ++r2) {
        const float inv = 1.0f / __shfl(lt, 4 * lg + r2);
        #pragma unroll
        for (int dt = 0; dt < 4; ++dt)
            yb[(4 * lg + r2) * 72 + dt * 16 + lr] =
                __builtin_bit_cast(unsigned short, (_Float16)(o_acc[dt][r2] * inv));
    }
    {
        const int px = lane >> 2, ch = lane & 3;
        f16x8 y0 = *(const f16x8*)&yb[px * 72 + ch * 16];
        f16x8 y1 = *(const f16x8*)&yb[px * 72 + ch * 16 + 8];
        unsigned short* op = Yh + ((size_t)b * HW_ + q0 + px) * CI_ + ch * 16;
        *(f16x8*)op       = y0;
        *(f16x8*)(op + 8) = y1;
    }
#undef STAGE
#undef COMPUTE
}

// ---------------------------------------------------------------------------
// Kernel 4: 1x1 conv back to 128 channels as fp16 MFMA GEMM (fp32 out for GN).
// Block = 4 waves x 16 px; grid 144 x 4. A = fp16 wW rows, B = fp16 Y rows.
// D[o=4lg+r][n=lr] -> coalesced 64B fp32 stores into Z[b][o][n].
// ---------------------------------------------------------------------------
__global__ __launch_bounds__(256) void conv2_kernel(
    const unsigned short* __restrict__ Yh, const unsigned short* __restrict__ wWh,
    const float* __restrict__ bW, float* __restrict__ Zg)
{
    const int t    = threadIdx.x;
    const int wv   = t >> 6;
    const int lane = t & 63;
    const int lr   = lane & 15;
    const int lg   = lane >> 4;
    const int b    = blockIdx.y;
    const int n0   = blockIdx.x * 64 + wv * 16;

    // B fragments: Y[n0+lr][u*32 + lg*8 ..]
    f16x8 ya[2];
    #pragma unroll
    for (int u = 0; u < 2; ++u)
        ya[u] = *(const f16x8*)(Yh + ((size_t)b * HW_ + n0 + lr) * CI_ + u * 32 + lg * 8);

    float* Zb = Zg + (size_t)b * C_ * HW_ + n0 + lr;
    #pragma unroll
    for (int ot = 0; ot < 8; ++ot) {
        f32x4 D = (f32x4){0.f, 0.f, 0.f, 0.f};
        #pragma unroll
        for (int u = 0; u < 2; ++u) {
            f16x8 wa = *(const f16x8*)&wWh[(ot * 16 + lr) * CI_ + u * 32 + lg * 8];
            D = mfma16h(wa, ya[u], D);
        }
        #pragma unroll
        for (int r2 = 0; r2 < 4; ++r2) {
            const int o = ot * 16 + 4 * lg + r2;
            Zb[(size_t)o * HW_] = D[r2] + bW[o];
        }
    }
}

// ---------------------------------------------------------------------------
// Kernel 5: GroupNorm stats (deterministic).
// ---------------------------------------------------------------------------
__global__ __launch_bounds__(256) void stats_kernel(
    const float* __restrict__ Zg, float* __restrict__ stats)
{
    const int t  = threadIdx.x;
    const int gr = blockIdx.x;
    const int b  = blockIdx.y;
    const float4* zp = (const float4*)(Zg + ((size_t)b * C_ + gr * 4) * HW_);
    float s = 0.f, ss = 0.f;
    for (int i = t; i < HW_; i += 256) {
        const float4 v = zp[i];
        s  += v.x + v.y + v.z + v.w;
        ss += v.x*v.x + v.y*v.y + v.z*v.z + v.w*v.w;
    }
    __shared__ float rs[256], rq[256];
    rs[t] = s; rq[t] = ss;
    __syncthreads();
    for (int off = 128; off > 0; off >>= 1) {
        if (t < off) { rs[t] += rs[t + off]; rq[t] += rq[t + off]; }
        __syncthreads();
    }
    if (t == 0) {
        const float invn = 1.0f / (4 * HW_);
        const float mean = rs[0] * invn;
        const float var  = rq[0] * invn - mean * mean;
        stats[((size_t)b * GROUPS_ + gr) * 2 + 0] = mean;
        stats[((size_t)b * GROUPS_ + gr) * 2 + 1] = rsqrtf(var + EPS_);
    }
}

// ---------------------------------------------------------------------------
// Kernel 6: normalize + affine + residual.
// ---------------------------------------------------------------------------
__global__ __launch_bounds__(256) void final_kernel(
    const float* __restrict__ Zg, const float* __restrict__ xg,
    const float* __restrict__ stats, const float* __restrict__ gnw,
    const float* __restrict__ gnb, float* __restrict__ out)
{
    const size_t i4  = (size_t)blockIdx.x * 256 + threadIdx.x;
    const size_t idx = i4 * 4;
    const int bc = (int)(i4 / (HW_ / 4));
    const int c  = bc & 127;
    const int b  = bc >> 7;
    const int g  = c >> 2;
    const float mean = stats[((size_t)b * GROUPS_ + g) * 2 + 0];
    const float rstd = stats[((size_t)b * GROUPS_ + g) * 2 + 1];
    const float sc = rstd * gnw[c];
    const float sh = gnb[c] - mean * sc;
    const float4 z  = *(const float4*)(Zg + idx);
    const float4 xv = *(const float4*)(xg + idx);
    float4 o;
    o.x = z.x * sc + sh + xv.x;
    o.y = z.y * sc + sh + xv.y;
    o.z = z.z * sc + sh + xv.z;
    o.w = z.w * sc + sh + xv.w;
    *(float4*)(out + idx) = o;
}

// ---------------------------------------------------------------------------
extern "C" void kernel_launch(void* const* d_in, const int* in_sizes, int n_in,
                              void* d_out, int out_size, void* d_ws, size_t ws_size,
                              hipStream_t stream)
{
    const float* x       = (const float*)d_in[0];
    const float* w_theta = (const float*)d_in[1];
    const float* b_theta = (const float*)d_in[2];
    const float* w_phi   = (const float*)d_in[3];
    const float* b_phi   = (const float*)d_in[4];
    const float* w_g     = (const float*)d_in[5];
    const float* b_g     = (const float*)d_in[6];
    const float* w_W     = (const float*)d_in[7];
    const float* b_W     = (const float*)d_in[8];
    const float* gn_w    = (const float*)d_in[9];
    const float* gn_b    = (const float*)d_in[10];
    float* out = (float*)d_out;
    char* wsb  = (char*)d_ws;

    // workspace layout (bytes)
    unsigned short* Q    = (unsigned short*)(wsb);             //  4,718,592
    unsigned short* K    = (unsigned short*)(wsb +  4718592);  //  1,179,648
    unsigned short* Vt   = (unsigned short*)(wsb +  5898240);  //  1,179,648
    unsigned short* phiF = (unsigned short*)(wsb +  7077888);  //  4,718,592
    unsigned short* gF   = (unsigned short*)(wsb + 11796480);  //  4,718,592
    unsigned short* Yh   = (unsigned short*)(wsb +  7077888);  //  2,359,296 (aliases phiF, dead after pool)
    float* Z             = (float*)(wsb + 16515072);           // 18,874,368
    float* stats         = (float*)(wsb + 35389440);           //  1 KB
    unsigned short* Whall= (unsigned short*)(wsb + 35390464);  //  65,536
    unsigned short* wWh  = Whall + 24576;

    wprep_kernel<<<128, 256, 0, stream>>>(w_theta, w_phi, w_g, w_W, Whall);
    proj_kernel <<<dim3(HW_ / 64, B_), 256, 0, stream>>>(
        x, Whall, b_theta, b_phi, b_g, Q, phiF, gF);
    pool_kernel <<<dim3(NP_ * CI_ / 256, B_, 2), 256, 0, stream>>>(phiF, gF, K, Vt);
    attn_kernel <<<dim3(HW_ / 16, B_), 64, 0, stream>>>(Q, K, Vt, Yh);
    conv2_kernel<<<dim3(HW_ / 64, B_), 256, 0, stream>>>(Yh, wWh, b_W, Z);
    stats_kernel<<<dim3(GROUPS_, B_), 256, 0, stream>>>(Z, stats);
    final_kernel<<<dim3((B_ * C_ * HW_) / 1024, 1), 256, 0, stream>>>(
        Z, x, stats, gn_w, gn_b, out);
}

// Round 12
// 116.992 us; speedup vs baseline: 1.4413x; 1.2613x over previous
//
#include <hip/hip_runtime.h>
#include <math.h>

#define B_ 4
#define C_ 128
#define CI_ 64
#define H_ 96
#define W_ 96
#define HW_ (H_*W_)      // 9216
#define NP_ 2304         // 48*48
#define GROUPS_ 32
#define EPS_ 1e-5f
#define KVT_ 32          // KV tile rows
#define NT_ (NP_/KVT_)   // 72 tiles

typedef _Float16 f16x8 __attribute__((ext_vector_type(8)));
typedef _Float16 f16x2 __attribute__((ext_vector_type(2)));
typedef __attribute__((ext_vector_type(4))) float f32x4;

__device__ inline f32x4 mfma16h(f16x8 a, f16x8 b, f32x4 c) {
    return __builtin_amdgcn_mfma_f32_16x16x32_f16(a, b, c, 0, 0, 0);
}
__device__ inline float h2f(unsigned short s) {
    return (float)__builtin_bit_cast(_Float16, s);
}
__device__ inline unsigned pk_f16(float a, float b) {     // pack 2 f32 -> 2 f16 (RTZ)
    return __builtin_bit_cast(unsigned, __builtin_amdgcn_cvt_pkrtz(a, b));
}
__device__ inline f16x8 pk8(float v0, float v1, float v2, float v3,
                            float v4, float v5, float v6, float v7) {
    uint4 u = { pk_f16(v0, v1), pk_f16(v2, v3), pk_f16(v4, v5), pk_f16(v6, v7) };
    return __builtin_bit_cast(f16x8, u);
}
// global -> LDS direct DMA, 16B/lane. LDS dest = wave-uniform base + lane*16.
__device__ inline void gload_lds16(const void* g, void* l) {
    __builtin_amdgcn_global_load_lds(
        (const __attribute__((address_space(1))) void*)reinterpret_cast<uintptr_t>(g),
        (__attribute__((address_space(3))) void*)(unsigned)reinterpret_cast<uintptr_t>(l),
        16, 0, 0);
}

// ---------------------------------------------------------------------------
// Kernel 0: cast the 4 weight matrices to fp16 (Whall[32768]).
// ---------------------------------------------------------------------------
__global__ __launch_bounds__(256) void wprep_kernel(
    const float* __restrict__ w_theta, const float* __restrict__ w_phi,
    const float* __restrict__ w_g,     const float* __restrict__ w_W,
    unsigned short* __restrict__ Whall)
{
    const int idx = blockIdx.x * 256 + threadIdx.x;   // 0..32767
    float v;
    if      (idx <  8192) v = w_theta[idx];
    else if (idx < 16384) v = w_phi[idx - 8192];
    else if (idx < 24576) v = w_g[idx - 16384];
    else                  v = w_W[idx - 24576];
    Whall[idx] = __builtin_bit_cast(unsigned short, (_Float16)v);
}

// ---------------------------------------------------------------------------
// Kernel 1: fused 3-way 1x1 conv projections as fp16 MFMA GEMM.
// ---------------------------------------------------------------------------
__global__ __launch_bounds__(256) void proj_kernel(
    const float* __restrict__ x, const unsigned short* __restrict__ Whall,
    const float* __restrict__ b_theta, const float* __restrict__ b_phi,
    const float* __restrict__ b_g,
    unsigned short* __restrict__ Qo, unsigned short* __restrict__ phiF,
    unsigned short* __restrict__ gF)
{
    __shared__ __align__(16) unsigned short pb[4][16 * 72];   // per-wave bounce

    const int t    = threadIdx.x;
    const int wv   = t >> 6;
    const int lane = t & 63;
    const int lr   = lane & 15;
    const int lg   = lane >> 4;
    const int b    = blockIdx.y;
    const int px0  = blockIdx.x * 64 + wv * 16;

    const float* xb = x + (size_t)b * C_ * HW_ + px0 + lr;
    f16x8 xa[4];
    #pragma unroll
    for (int u = 0; u < 4; ++u) {
        const float* p = xb + (size_t)(u * 32 + lg * 8) * HW_;
        xa[u] = pk8(p[0], p[(size_t)HW_], p[2 * (size_t)HW_], p[3 * (size_t)HW_],
                    p[4 * (size_t)HW_], p[5 * (size_t)HW_], p[6 * (size_t)HW_],
                    p[7 * (size_t)HW_]);
    }

    #pragma unroll
    for (int mat = 0; mat < 3; ++mat) {
        const unsigned short* Whp = Whall + mat * 8192;
        const float* bsel = (mat == 0) ? b_theta : (mat == 1) ? b_phi : b_g;
        unsigned short* osel = (mat == 0) ? Qo : (mat == 1) ? phiF : gF;

        f32x4 D[4];
        #pragma unroll
        for (int ct = 0; ct < 4; ++ct) D[ct] = (f32x4){0.f, 0.f, 0.f, 0.f};
        #pragma unroll
        for (int u = 0; u < 4; ++u)
            #pragma unroll
            for (int ct = 0; ct < 4; ++ct) {
                f16x8 wb = *(const f16x8*)&Whp[(ct * 16 + lr) * 128 + u * 32 + lg * 8];
                D[ct] = mfma16h(xa[u], wb, D[ct]);
            }

        #pragma unroll
        for (int ct = 0; ct < 4; ++ct) {
            const float bi = bsel[ct * 16 + lr];
            #pragma unroll
            for (int r2 = 0; r2 < 4; ++r2)
                pb[wv][(4 * lg + r2) * 72 + ct * 16 + lr] =
                    __builtin_bit_cast(unsigned short, (_Float16)(D[ct][r2] + bi));
        }
        {
            const int px = lane >> 2, ch = lane & 3;
            f16x8 y0 = *(const f16x8*)&pb[wv][px * 72 + ch * 16];
            f16x8 y1 = *(const f16x8*)&pb[wv][px * 72 + ch * 16 + 8];
            unsigned short* op = osel + ((size_t)b * HW_ + px0 + px) * CI_ + ch * 16;
            *(f16x8*)op       = y0;
            *(f16x8*)(op + 8) = y1;
        }
    }
}

// ---------------------------------------------------------------------------
// Kernel 2: 2x2 maxpool (fp16, exact). K stays [b][m][ci].
// V -> [b][ci][m'] transposed + per-32-group permuted (PV k-order match).
// ---------------------------------------------------------------------------
__global__ __launch_bounds__(256) void pool_kernel(
    const unsigned short* __restrict__ phiF, const unsigned short* __restrict__ gF,
    unsigned short* __restrict__ Ko, unsigned short* __restrict__ Vt)
{
    const int t   = threadIdx.x;
    const int b   = blockIdx.y;
    const int mat = blockIdx.z;                 // 0 -> K, 1 -> V^T(permuted)
    const int idx = blockIdx.x * 256 + t;       // 0..147455
    int m, ci;
    if (mat == 0) { m = idx >> 6; ci = idx & 63; }
    else          { ci = idx / NP_; m = idx - ci * NP_; }
    const int ph = m / 48, pw = m % 48;
    const int n00 = (ph * 2) * W_ + pw * 2;
    const unsigned short* src = mat ? gF : phiF;
    const unsigned short* p = src + ((size_t)b * HW_ + n00) * CI_ + ci;
    float v = fmaxf(fmaxf(h2f(p[0]), h2f(p[CI_])),
                    fmaxf(h2f(p[(size_t)W_ * CI_]), h2f(p[(size_t)(W_ + 1) * CI_])));
    unsigned short r = __builtin_bit_cast(unsigned short, (_Float16)v); // exact
    if (mat == 0) {
        Ko[((size_t)b * NP_ + m) * CI_ + ci] = r;
    } else {
        const int ms = (m & ~31) | (8 * ((m >> 2) & 3) + 4 * ((m >> 4) & 1) + (m & 3));
        Vt[((size_t)b * CI_ + ci) * NP_ + ms] = r;
    }
}

// ---------------------------------------------------------------------------
// Kernel 3: fp16 MFMA flash attention — 2-wave blocks with SHARED staging.
// Wave 0 DMAs the K tile, wave 1 the V tile; both consume both (halves the
// per-q-row L2 staging traffic vs R10's wave-private tiles). 1152 blocks x
// 2 waves = 9 waves/CU. Sync = raw s_barrier + manual counted vmcnt(4)
// (NOT __syncthreads: it drains vmcnt to 0 and kills the prefetch).
// In-register P feeds PV (V pre-permuted by pool). Output Y fp16.
// ---------------------------------------------------------------------------
__global__ __launch_bounds__(128) void attn_kernel(
    const unsigned short* __restrict__ Qg, const unsigned short* __restrict__ Kg,
    const unsigned short* __restrict__ Vt, unsigned short* __restrict__ Yh)
{
    __shared__ unsigned char Klds[2][4096];   // [buf][32 k-rows x 128B]
    __shared__ unsigned char Vlds[2][4096];   // [buf][64 d-rows x  64B]

    const int t    = threadIdx.x;
    const int wv   = t >> 6;
    const int lane = t & 63;
    const int lr   = lane & 15;
    const int lg   = lane >> 4;
    const int b    = blockIdx.y;
    const int q0   = blockIdx.x * 32 + wv * 16;

    const int krow = lane >> 3;                       // 0..7 (K: 8 rows/load)
    const int kchk = (lane & 7) ^ krow;               // K source 16B-chunk
    const int vrow = lane >> 2;                       // 0..15 (V: 16 rows/load)
    const int vchk = (lane & 3) ^ (vrow & 3);         // V source 16B-chunk

    const unsigned short* Kb = Kg + (size_t)b * NP_ * CI_;
    const unsigned short* Vb = Vt + (size_t)b * CI_ * NP_;

    f16x8 qf[2];
    #pragma unroll
    for (int u = 0; u < 2; ++u)
        qf[u] = *(const f16x8*)(Qg + ((size_t)b * HW_ + q0 + lr) * CI_ + u * 32 + lg * 8);

    f32x4 o_acc[4];
    #pragma unroll
    for (int dt = 0; dt < 4; ++dt) o_acc[dt] = (f32x4){0.f, 0.f, 0.f, 0.f};
    float mrun = -1e30f, lrun = 0.f;

#define STAGE(BUF, TT)                                                          \
    {                                                                           \
        const int kv0_ = (TT) * KVT_;                                           \
        if (wv == 0) {                                                          \
            _Pragma("unroll")                                                   \
            for (int i = 0; i < 4; ++i)                                         \
                gload_lds16(Kb + (size_t)(kv0_ + 8 * i + krow) * CI_ + kchk * 8,\
                            &Klds[BUF][i * 1024]);                              \
        } else {                                                                \
            _Pragma("unroll")                                                   \
            for (int i = 0; i < 4; ++i)                                         \
                gload_lds16(Vb + (size_t)(16 * i + vrow) * NP_ + kv0_ + vchk * 8,\
                            &Vlds[BUF][i * 1024]);                              \
        }                                                                       \
    }

#define COMPUTE(BUF)                                                            \
    {                                                                           \
        f16x8 kf[2][2];                                                         \
        _Pragma("unroll")                                                       \
        for (int u = 0; u < 2; ++u)                                             \
            _Pragma("unroll")                                                   \
            for (int k4 = 0; k4 < 2; ++k4)                                      \
                kf[u][k4] = *(const f16x8*)&Klds[BUF][(k4 * 16 + lr) * 128      \
                                + (((4 * u + lg) ^ (lr & 7)) << 4)];            \
        f32x4 s[2];                                                             \
        s[0] = (f32x4){0.f, 0.f, 0.f, 0.f};                                     \
        s[1] = (f32x4){0.f, 0.f, 0.f, 0.f};                                     \
        __builtin_amdgcn_s_setprio(1);                                          \
        _Pragma("unroll")                                                       \
        for (int u = 0; u < 2; ++u) {                                           \
            s[0] = mfma16h(kf[u][0], qf[u], s[0]);                              \
            s[1] = mfma16h(kf[u][1], qf[u], s[1]);                              \
        }                                                                       \
        __builtin_amdgcn_s_setprio(0);                                          \
        float tmax = fmaxf(fmaxf(fmaxf(s[0][0], s[0][1]),                       \
                                 fmaxf(s[0][2], s[0][3])),                      \
                           fmaxf(fmaxf(s[1][0], s[1][1]),                       \
                                 fmaxf(s[1][2], s[1][3])));                     \
        if (!__all(tmax <= mrun + 8.0f)) {                                      \
            tmax = fmaxf(tmax, __shfl_xor(tmax, 16));                           \
            tmax = fmaxf(tmax, __shfl_xor(tmax, 32));                           \
            const float mnew = fmaxf(mrun, tmax);                               \
            const float sc = __expf(mrun - mnew);                               \
            lrun *= sc;                                                         \
            _Pragma("unroll")                                                   \
            for (int r2 = 0; r2 < 4; ++r2) {                                    \
                const float scb = __shfl(sc, 4 * lg + r2);                      \
                _Pragma("unroll")                                               \
                for (int dt = 0; dt < 4; ++dt) o_acc[dt][r2] *= scb;            \
            }                                                                   \
            mrun = mnew;                                                        \
        }                                                                       \
        const float e00 = __expf(s[0][0] - mrun);                               \
        const float e01 = __expf(s[0][1] - mrun);                               \
        const float e02 = __expf(s[0][2] - mrun);                               \
        const float e03 = __expf(s[0][3] - mrun);                               \
        const float e10 = __expf(s[1][0] - mrun);                               \
        const float e11 = __expf(s[1][1] - mrun);                               \
        const float e12 = __expf(s[1][2] - mrun);                               \
        const float e13 = __expf(s[1][3] - mrun);                               \
        lrun += ((e00 + e01) + (e02 + e03)) + ((e10 + e11) + (e12 + e13));      \
        f16x8 pf = pk8(e00, e01, e02, e03, e10, e11, e12, e13);                 \
        __builtin_amdgcn_s_setprio(1);                                          \
        _Pragma("unroll")                                                       \
        for (int dt = 0; dt < 4; ++dt) {                                        \
            const int vrow_ = dt * 16 + lr;                                     \
            f16x8 vf = *(const f16x8*)&Vlds[BUF][vrow_ * 64                     \
                            + (((lg ^ (lr & 3))) << 4)];                        \
            o_acc[dt] = mfma16h(pf, vf, o_acc[dt]);                             \
        }                                                                       \
        __builtin_amdgcn_s_setprio(0);                                          \
    }

    STAGE(0, 0);
    STAGE(1, 1);

    for (int it = 0; it < NT_ / 2; ++it) {
        const int t0 = 2 * it;
        // own outstanding: tiles t0 (4) + t0+1 (4) -> wait 4 leaves next flying
        asm volatile("s_waitcnt vmcnt(4)" ::: "memory");
        __builtin_amdgcn_s_barrier();            // partner's tile-t0 loads landed too
        COMPUTE(0);
        __builtin_amdgcn_s_barrier();            // both waves done reading buf 0
        if (t0 + 2 < NT_) STAGE(0, t0 + 2);
        if (it == NT_ / 2 - 1) {
            asm volatile("s_waitcnt vmcnt(0)" ::: "memory");
        } else {
            asm volatile("s_waitcnt vmcnt(4)" ::: "memory");
        }
        __builtin_amdgcn_s_barrier();
        COMPUTE(1);
        __builtin_amdgcn_s_barrier();
        if (t0 + 3 < NT_) STAGE(1, t0 + 3);
    }

    // ---- finalize: reduce l, scale, bounce through own Klds slice, store fp16
    float lt = lrun;
    lt += __shfl_xor(lt, 16);
    lt += __shfl_xor(lt, 32);
    unsigned short* yb = (unsigned short*)&Klds[wv][0];   // [16][72] halves
    #pragma unroll
    for (int r2 = 0; r2 < 4; ++r2) {
        const float inv = 1.0f / __shfl(lt, 4 * lg + r2);
        #pragma unroll
        for (int dt = 0; dt < 4; ++dt)
            yb[(4 * lg + r2) * 72 + dt * 16 + lr] =
                __builtin_bit_cast(unsigned short, (_Float16)(o_acc[dt][r2] * inv));
    }
    {
        const int px = lane >> 2, ch = lane & 3;
        f16x8 y0 = *(const f16x8*)&yb[px * 72 + ch * 16];
        f16x8 y1 = *(const f16x8*)&yb[px * 72 + ch * 16 + 8];
        unsigned short* op = Yh + ((size_t)b * HW_ + q0 + px) * CI_ + ch * 16;
        *(f16x8*)op       = y0;
        *(f16x8*)(op + 8) = y1;
    }
#undef STAGE
#undef COMPUTE
}

// ---------------------------------------------------------------------------
// Kernel 4: 1x1 conv back (fp16 MFMA, fp32 out) + GN PARTIAL SUMS per block.
// Partials: group g = ot*4+lg channels live in one lane-group -> in-wave
// shfl reduce over the 16 px, LDS-combine 4 waves, write [b][blk][32][2].
// ---------------------------------------------------------------------------
__global__ __launch_bounds__(256) void conv2_kernel(
    const unsigned short* __restrict__ Yh, const unsigned short* __restrict__ wWh,
    const float* __restrict__ bW, float* __restrict__ Zg, float* __restrict__ gpart)
{
    __shared__ float wpart[4][32][2];

    const int t    = threadIdx.x;
    const int wv   = t >> 6;
    const int lane = t & 63;
    const int lr   = lane & 15;
    const int lg   = lane >> 4;
    const int b    = blockIdx.y;
    const int n0   = blockIdx.x * 64 + wv * 16;

    f16x8 ya[2];
    #pragma unroll
    for (int u = 0; u < 2; ++u)
        ya[u] = *(const f16x8*)(Yh + ((size_t)b * HW_ + n0 + lr) * CI_ + u * 32 + lg * 8);

    float* Zb = Zg + (size_t)b * C_ * HW_ + n0 + lr;
    #pragma unroll
    for (int ot = 0; ot < 8; ++ot) {
        f32x4 D = (f32x4){0.f, 0.f, 0.f, 0.f};
        #pragma unroll
        for (int u = 0; u < 2; ++u) {
            f16x8 wa = *(const f16x8*)&wWh[(ot * 16 + lr) * CI_ + u * 32 + lg * 8];
            D = mfma16h(wa, ya[u], D);
        }
        float zs = 0.f, zq = 0.f;
        #pragma unroll
        for (int r2 = 0; r2 < 4; ++r2) {
            const int o = ot * 16 + 4 * lg + r2;
            const float z = D[r2] + bW[o];
            Zb[(size_t)o * HW_] = z;
            zs += z;
            zq += z * z;
        }
        // reduce over the wave's 16 px (lr lanes)
        zs += __shfl_xor(zs, 1);  zq += __shfl_xor(zq, 1);
        zs += __shfl_xor(zs, 2);  zq += __shfl_xor(zq, 2);
        zs += __shfl_xor(zs, 4);  zq += __shfl_xor(zq, 4);
        zs += __shfl_xor(zs, 8);  zq += __shfl_xor(zq, 8);
        if (lr == 0) {
            wpart[wv][ot * 4 + lg][0] = zs;
            wpart[wv][ot * 4 + lg][1] = zq;
        }
    }
    __syncthreads();
    if (t < 64) {
        const int g = t >> 1, w = t & 1;
        const float v = wpart[0][g][w] + wpart[1][g][w]
                      + wpart[2][g][w] + wpart[3][g][w];
        gpart[(((size_t)b * 144 + blockIdx.x) * 32 + g) * 2 + w] = v;
    }
}

// ---------------------------------------------------------------------------
// Kernel 5: fused GN stats-reduce + normalize + affine + residual.
// Block (c, b): tree-reduce the 144 partials of group c>>2, then stream the
// (b,c) row with perfect coalescing.
// ---------------------------------------------------------------------------
__global__ __launch_bounds__(256) void final_kernel(
    const float* __restrict__ Zg, const float* __restrict__ xg,
    const float* __restrict__ gpart, const float* __restrict__ gnw,
    const float* __restrict__ gnb, float* __restrict__ out)
{
    __shared__ float red[256][2];
    const int t = threadIdx.x;
    const int c = blockIdx.x;
    const int b = blockIdx.y;
    const int g = c >> 2;

    float v1 = 0.f, v2 = 0.f;
    if (t < 144) {
        v1 = gpart[(((size_t)b * 144 + t) * 32 + g) * 2 + 0];
        v2 = gpart[(((size_t)b * 144 + t) * 32 + g) * 2 + 1];
    }
    red[t][0] = v1; red[t][1] = v2;
    __syncthreads();
    for (int off = 128; off > 0; off >>= 1) {
        if (t < off) { red[t][0] += red[t + off][0]; red[t][1] += red[t + off][1]; }
        __syncthreads();
    }
    const float invn = 1.0f / (4 * HW_);
    const float mean = red[0][0] * invn;
    const float var  = red[0][1] * invn - mean * mean;
    const float rstd = rsqrtf(var + EPS_);
    const float sc = rstd * gnw[c];
    const float sh = gnb[c] - mean * sc;

    const float4* zp = (const float4*)(Zg + ((size_t)b * C_ + c) * HW_);
    const float4* xp = (const float4*)(xg + ((size_t)b * C_ + c) * HW_);
    float4*       op = (float4*)(out + ((size_t)b * C_ + c) * HW_);
    #pragma unroll
    for (int i = 0; i < HW_ / 4 / 256; ++i) {
        const int j = i * 256 + t;
        const float4 z  = zp[j];
        const float4 xv = xp[j];
        float4 o;
        o.x = z.x * sc + sh + xv.x;
        o.y = z.y * sc + sh + xv.y;
        o.z = z.z * sc + sh + xv.z;
        o.w = z.w * sc + sh + xv.w;
        op[j] = o;
    }
}

// ---------------------------------------------------------------------------
extern "C" void kernel_launch(void* const* d_in, const int* in_sizes, int n_in,
                              void* d_out, int out_size, void* d_ws, size_t ws_size,
                              hipStream_t stream)
{
    const float* x       = (const float*)d_in[0];
    const float* w_theta = (const float*)d_in[1];
    const float* b_theta = (const float*)d_in[2];
    const float* w_phi   = (const float*)d_in[3];
    const float* b_phi   = (const float*)d_in[4];
    const float* w_g     = (const float*)d_in[5];
    const float* b_g     = (const float*)d_in[6];
    const float* w_W     = (const float*)d_in[7];
    const float* b_W     = (const float*)d_in[8];
    const float* gn_w    = (const float*)d_in[9];
    const float* gn_b    = (const float*)d_in[10];
    float* out = (float*)d_out;
    char* wsb  = (char*)d_ws;

    // workspace layout (bytes)
    unsigned short* Q    = (unsigned short*)(wsb);             //  4,718,592
    unsigned short* K    = (unsigned short*)(wsb +  4718592);  //  1,179,648
    unsigned short* Vt   = (unsigned short*)(wsb +  5898240);  //  1,179,648
    unsigned short* phiF = (unsigned short*)(wsb +  7077888);  //  4,718,592
    unsigned short* gF   = (unsigned short*)(wsb + 11796480);  //  4,718,592
    unsigned short* Yh   = (unsigned short*)(wsb +  7077888);  //  2,359,296 (aliases phiF, dead after pool)
    float* gpart         = (float*)(wsb + 11796480);           //    147,456 (aliases gF, dead after pool)
    float* Z             = (float*)(wsb + 16515072);           // 18,874,368
    unsigned short* Whall= (unsigned short*)(wsb + 35390464);  //     65,536
    unsigned short* wWh  = Whall + 24576;

    wprep_kernel<<<128, 256, 0, stream>>>(w_theta, w_phi, w_g, w_W, Whall);
    proj_kernel <<<dim3(HW_ / 64, B_), 256, 0, stream>>>(
        x, Whall, b_theta, b_phi, b_g, Q, phiF, gF);
    pool_kernel <<<dim3(NP_ * CI_ / 256, B_, 2), 256, 0, stream>>>(phiF, gF, K, Vt);
    attn_kernel <<<dim3(HW_ / 32, B_), 128, 0, stream>>>(Q, K, Vt, Yh);
    conv2_kernel<<<dim3(HW_ / 64, B_), 256, 0, stream>>>(Yh, wWh, b_W, Z, gpart);
    final_kernel<<<dim3(C_, B_), 256, 0, stream>>>(Z, x, gpart, gn_w, gn_b, out);
}